// Round 1
// baseline (1230.639 us; speedup 1.0000x reference)
//
#include <hip/hip_runtime.h>
#include <stdint.h>
#include <math.h>

typedef unsigned long long ull;

#define DD 20000
#define NK 64
#define NB 4096
#define YN (NB * NK)              // 262144
#define TOTN (YN + NK * DD + 1)   // 1542145

// ws float offsets
#define Z_OFF 0
#define S_OFF 1280000
#define CV_OFF 2560000
#define CC_OFF 2564096
// ST (packed samples for GEMM) reuses Z_OFF after k_rows is done with Z.

// ---------------- threefry2x32, JAX partitionable scheme ----------------
// key = [0, 42] (jax.random.key(42)); counter = (hi=0, lo=j); bits = o0 ^ o1.
__device__ __forceinline__ uint32_t tf_bits(uint32_t j) {
  const uint32_t k0 = 0u, k1 = 42u;
  const uint32_t k2 = 0x1BD11BDAu ^ k0 ^ k1;
  uint32_t x0 = k0;       // hi(=0) + k0
  uint32_t x1 = j + k1;   // lo(=j) + k1
#define TFR(r) { x0 += x1; x1 = (x1 << r) | (x1 >> (32 - r)); x1 ^= x0; }
  TFR(13) TFR(15) TFR(26) TFR(6)
  x0 += k1; x1 += k2 + 1u;
  TFR(17) TFR(29) TFR(16) TFR(24)
  x0 += k2; x1 += k0 + 2u;
  TFR(13) TFR(15) TFR(26) TFR(6)
  x0 += k0; x1 += k1 + 3u;
  TFR(17) TFR(29) TFR(16) TFR(24)
  x0 += k1; x1 += k2 + 4u;
  TFR(13) TFR(15) TFR(26) TFR(6)
  x0 += k2; x1 += k0 + 5u;
#undef TFR
  return x0 ^ x1;
}

// ---------------- K1: z = (log(10*clip(softmax64(u@tinyW))) + gumbel)/new_temp
// block: 256 thr = 64 k-lanes x 4 waves; block covers 64 d (16 iters/wave).
__global__ __launch_bounds__(256) void k_z(
    const float* __restrict__ uu, const float* __restrict__ tw,
    const float* __restrict__ temp, float* __restrict__ Z) {
  __shared__ float tile[NK][65];  // +1 pad: conflict-free column writes
  const int tid = threadIdx.x;
  const int lane = tid & 63;      // = k
  const int wv = tid >> 6;
  const int d0 = blockIdx.x * 64;
  const float nt = fmaxf(0.1f, temp[0] * 0.99999f);
  float w[10];
#pragma unroll
  for (int i = 0; i < 10; ++i) w[i] = tw[i * NK + lane];
  for (int it = 0; it < 16; ++it) {
    const int dl = wv * 16 + it;
    const int d = d0 + dl;
    if (d < DD) {  // wave-uniform branch (same d across the wave)
      float m = 0.f;
#pragma unroll
      for (int i = 0; i < 10; ++i) m = fmaf(uu[d * 10 + i], w[i], m);
      float mx = m;
#pragma unroll
      for (int off = 32; off; off >>= 1) mx = fmaxf(mx, __shfl_xor(mx, off, 64));
      double e = exp((double)(m - mx));
      double ssum = e;
#pragma unroll
      for (int off = 32; off; off >>= 1) ssum += __shfl_xor(ssum, off, 64);
      float al = (float)(e / ssum);
      float c = fminf(fmaxf(al, 1e-7f), 0.9999999f);
      float lg = (float)log((double)(10.0f * c));
      const uint32_t bits = tf_bits((uint32_t)(lane * DD + d));
      float uf = __uint_as_float((bits >> 9) | 0x3f800000u) - 1.0f;
      float uv = fmaxf(1e-7f, uf * (1.0f - 1e-7f) + 1e-7f);
      float g = (float)(-log(-log((double)uv)));
      tile[lane][dl] = (lg + g) / nt;
    }
  }
  __syncthreads();
  for (int r0 = 0; r0 < NK; r0 += 4) {
    const int r = r0 + wv;
    const int d = d0 + lane;
    if (d < DD) Z[r * DD + d] = tile[r][lane];
  }
}

// ---------------- K2: per-row softmax over d + exact top-64 candidates ------
__global__ __launch_bounds__(256) void k_rows(
    const float* __restrict__ Z, float* __restrict__ S, float* __restrict__ disc,
    float* __restrict__ cv, int* __restrict__ cc) {
  const int k = blockIdx.x;
  const int tid = threadIdx.x;
  __shared__ float redf[256];
  __shared__ double redd[256];
  __shared__ ull keys[2048];  // 256 threads x top-8
  __shared__ ull wbest[4];
  const float* zr = Z + (size_t)k * DD;
  float* sr = S + (size_t)k * DD;
  float* dr = disc + (size_t)k * DD;
  // row max
  float mx = -1e30f;
  for (int d = tid; d < DD; d += 256) mx = fmaxf(mx, zr[d]);
  redf[tid] = mx;
  __syncthreads();
  for (int s = 128; s; s >>= 1) {
    if (tid < s) redf[tid] = fmaxf(redf[tid], redf[tid + s]);
    __syncthreads();
  }
  mx = redf[0];
  // row sum (f64)
  double psum = 0.0;
  for (int d = tid; d < DD; d += 256) psum += exp((double)(zr[d] - mx));
  redd[tid] = psum;
  __syncthreads();
  for (int s = 128; s; s >>= 1) {
    if (tid < s) redd[tid] += redd[tid + s];
    __syncthreads();
  }
  const double sumall = redd[0];
  // samples + zero discrete + per-thread sorted top-8
  float tv[8]; int tc[8];
#pragma unroll
  for (int s = 0; s < 8; ++s) { tv[s] = -1.f; tc[s] = 0; }
  for (int d = tid; d < DD; d += 256) {
    double e = exp((double)(zr[d] - mx));
    float svv = (float)(e / sumall);
    sr[d] = svv;
    dr[d] = 0.f;
    if (svv > tv[7]) {  // bubble-insert (strict >: equal values keep earlier d first)
      float cvr = svv; int ccr = d;
#pragma unroll
      for (int s = 0; s < 8; ++s) {
        bool sw = cvr > tv[s];
        float nv = sw ? cvr : tv[s]; int nc = sw ? ccr : tc[s];
        cvr = sw ? tv[s] : cvr; ccr = sw ? tc[s] : ccr;
        tv[s] = nv; tc[s] = nc;
      }
    }
  }
  // pack: valbits | (32767-col)<<11 | owner<<3 | slot  (tie -> lowest col)
#pragma unroll
  for (int s = 0; s < 8; ++s)
    keys[(tid << 3) + s] = (((ull)__float_as_uint(tv[s])) << 32)
                         | ((ull)(uint32_t)(32767 - tc[s]) << 11)
                         | ((ull)tid << 3) | (ull)s;
  __syncthreads();
  // 64 extractions of the global (row) max over the 2048 candidates
  for (int t = 0; t < NK; ++t) {
    ull best = 0;
#pragma unroll
    for (int s = 0; s < 8; ++s) { ull kk = keys[(tid << 3) + s]; if (kk > best) best = kk; }
#pragma unroll
    for (int off = 32; off; off >>= 1) { ull o = __shfl_xor(best, off, 64); if (o > best) best = o; }
    if ((tid & 63) == 0) wbest[tid >> 6] = best;
    __syncthreads();
    ull win = wbest[0];
#pragma unroll
    for (int wI = 1; wI < 4; ++wI) if (wbest[wI] > win) win = wbest[wI];
    const uint32_t lo = (uint32_t)win;
    const int slot = lo & 7;
    const int owner = (lo >> 3) & 255;
    const int col = 32767 - (int)(lo >> 11);
    if (tid == 0) {
      cv[(k << 6) + t] = __uint_as_float((uint32_t)(win >> 32));
      cc[(k << 6) + t] = col;
    }
    if (tid == owner) keys[(owner << 3) + slot] = 0;
    __syncthreads();
  }
}

// ---------------- K3: samples (k-major) -> packed [d/4][64k][4] for GEMM ----
__global__ __launch_bounds__(256) void k_tr(const float* __restrict__ S,
                                            float* __restrict__ ST) {
  __shared__ float tile[NK][132];
  const int tid = threadIdx.x;
  const int d0 = blockIdx.x * 128;
  const int validD = min(128, DD - d0);
  const int col = tid & 127;
  const int rhalf = tid >> 7;
  for (int r0 = 0; r0 < NK; r0 += 2) {
    const int r = r0 + rhalf;
    if (col < validD) tile[r][col] = S[(size_t)r * DD + d0 + col];
  }
  __syncthreads();
  const int g0 = d0 >> 2;
  const int ng = validD >> 2;
  for (int g = 0; g < ng; ++g)
    ST[(size_t)(g0 + g) * 256 + tid] = tile[tid >> 2][(g << 2) | (tid & 3)];
}

// ---------------- K4: greedy bipartite argmax-and-mask (1 wave, lane=row) ---
__global__ __launch_bounds__(64) void k_greedy(
    const float* __restrict__ cv, const int* __restrict__ cc,
    const float* __restrict__ temp, float* __restrict__ out) {
  __shared__ float v[NK][NK];
  __shared__ int c[NK][NK];
  __shared__ unsigned char used[DD];
  const int lane = threadIdx.x;
  for (int i = lane; i < DD; i += 64) used[i] = 0;
  for (int i = 0; i < NK; ++i) { v[i][lane] = cv[(i << 6) + lane]; c[i][lane] = cc[(i << 6) + lane]; }
  __syncthreads();
  int ptr = 0;
  bool done = false;
  for (int t = 0; t < NK; ++t) {
    ull key = 0;
    if (!done) {
      while (ptr < NK && used[c[lane][ptr]]) ++ptr;
      if (ptr < NK) {
        // val | (63-row)<<15 | (32767-col): flat row-major argmax tie-break
        key = (((ull)__float_as_uint(v[lane][ptr])) << 21)
            | ((ull)(uint32_t)(63 - lane) << 15)
            | (ull)(uint32_t)(32767 - c[lane][ptr]);
      }
    }
#pragma unroll
    for (int off = 32; off; off >>= 1) { ull o = __shfl_xor(key, off, 64); if (o > key) key = o; }
    const int col = 32767 - (int)(key & 0x7FFF);
    const int row = 63 - (int)((key >> 15) & 63);
    if (lane == row) done = true;
    if (lane == 0) { used[col] = 1; out[YN + (size_t)row * DD + col] = 1.0f; }
    __syncthreads();
  }
  if (lane == 0) out[TOTN - 1] = fmaxf(0.1f, temp[0] * 0.99999f);
}

// ---------------- K5: zero Y (atomic accumulation target) -------------------
__global__ __launch_bounds__(256) void k_zeroY(float* __restrict__ out) {
  const int i = blockIdx.x * 256 + threadIdx.x;  // grid sized to YN/4 exactly
  ((float4*)out)[i] = make_float4(0.f, 0.f, 0.f, 0.f);
}

// ---------------- K6: Y = X @ samples^T (f32 vector, split-K=8) -------------
// lane = k (64), 4 waves x 16 batch rows = 64 rows/block; ST chunk in LDS.
__global__ __launch_bounds__(256) void k_gemm(
    const float* __restrict__ X, const float* __restrict__ ST,
    float* __restrict__ Y) {
  __shared__ float lds[240 * 64];  // 61440 B -> 2 blocks/CU
  const int tid = threadIdx.x;
  const int lane = tid & 63;
  const int wv = __builtin_amdgcn_readfirstlane(tid >> 6);
  const int dsp = blockIdx.x;  // 0..7 K-split
  const int bg = blockIdx.y;   // 0..63 batch groups of 64
  const int dStart = dsp * 2500;
  const int dEnd = dStart + 2500;
  const int bBase = bg * 64 + wv * 16;
  float acc[16];
#pragma unroll
  for (int i = 0; i < 16; ++i) acc[i] = 0.f;
  for (int c0 = dStart; c0 < dEnd; c0 += 240) {
    const int cd = min(240, dEnd - c0);
    const int nf4 = cd << 4;  // cd*64 floats / 4
    const float4* src = (const float4*)(ST + (size_t)(c0 >> 2) * 256);
    float4* dst = (float4*)lds;
    for (int i = tid; i < nf4; i += 256) dst[i] = src[i];
    __syncthreads();
    const int ng = cd >> 2;
    const float* xb = X + (size_t)bBase * DD + c0;
    for (int g = 0; g < ng; ++g) {
      const float4 sv = ((const float4*)lds)[(g << 6) + lane];
#pragma unroll
      for (int i = 0; i < 16; ++i) {
        const float4 xv = *(const float4*)(xb + (size_t)i * DD + (g << 2));
        acc[i] = fmaf(xv.x, sv.x, acc[i]);
        acc[i] = fmaf(xv.y, sv.y, acc[i]);
        acc[i] = fmaf(xv.z, sv.z, acc[i]);
        acc[i] = fmaf(xv.w, sv.w, acc[i]);
      }
    }
    __syncthreads();
  }
#pragma unroll
  for (int i = 0; i < 16; ++i)
    atomicAdd(&Y[(size_t)(bBase + i) * 64 + lane], acc[i]);
}

extern "C" void kernel_launch(void* const* d_in, const int* in_sizes, int n_in,
                              void* d_out, int out_size, void* d_ws, size_t ws_size,
                              hipStream_t stream) {
  (void)in_sizes; (void)n_in; (void)out_size; (void)ws_size;
  const float* X = (const float*)d_in[0];
  const float* uu = (const float*)d_in[1];
  const float* tw = (const float*)d_in[2];
  const float* temp = (const float*)d_in[3];
  float* out = (float*)d_out;
  float* W = (float*)d_ws;
  float* Z = W + Z_OFF;
  float* S = W + S_OFF;
  float* CV = W + CV_OFF;
  int* CC = (int*)(W + CC_OFF);
  float* ST = Z;  // reuse Z region after k_rows

  hipLaunchKernelGGL(k_zeroY, dim3(YN / 1024), dim3(256), 0, stream, out);
  hipLaunchKernelGGL(k_z, dim3(313), dim3(256), 0, stream, uu, tw, temp, Z);
  hipLaunchKernelGGL(k_rows, dim3(64), dim3(256), 0, stream, Z, S, out + YN, CV, CC);
  hipLaunchKernelGGL(k_tr, dim3(157), dim3(256), 0, stream, S, ST);
  hipLaunchKernelGGL(k_greedy, dim3(1), dim3(64), 0, stream, CV, CC, temp, out);
  hipLaunchKernelGGL(k_gemm, dim3(8, 64), dim3(256), 0, stream, X, ST, out);
}

// Round 2
// 660.414 us; speedup vs baseline: 1.8634x; 1.8634x over previous
//
#include <hip/hip_runtime.h>
#include <stdint.h>
#include <math.h>

typedef unsigned long long ull;
typedef __attribute__((ext_vector_type(8))) short short8;
typedef __attribute__((ext_vector_type(4))) float f32x4;

#define DD 20000
#define NK 64
#define NB 4096
#define YN (NB * NK)              // 262144
#define TOTN (YN + NK * DD + 1)   // 1542145
#define KS 32                     // split-K factor for the GEMM

// ws float offsets
#define Z_OFF 0
#define CV_OFF 1280000
#define CC_OFF 1284096
#define SB_OFF 1288192            // bf16 samples [64][20000] (ushort)

// ---------------- threefry2x32, JAX partitionable scheme ----------------
__device__ __forceinline__ uint32_t tf_bits(uint32_t j) {
  const uint32_t k0 = 0u, k1 = 42u;
  const uint32_t k2 = 0x1BD11BDAu ^ k0 ^ k1;
  uint32_t x0 = k0;
  uint32_t x1 = j + k1;
#define TFR(r) { x0 += x1; x1 = (x1 << r) | (x1 >> (32 - r)); x1 ^= x0; }
  TFR(13) TFR(15) TFR(26) TFR(6)
  x0 += k1; x1 += k2 + 1u;
  TFR(17) TFR(29) TFR(16) TFR(24)
  x0 += k2; x1 += k0 + 2u;
  TFR(13) TFR(15) TFR(26) TFR(6)
  x0 += k0; x1 += k1 + 3u;
  TFR(17) TFR(29) TFR(16) TFR(24)
  x0 += k1; x1 += k2 + 4u;
  TFR(13) TFR(15) TFR(26) TFR(6)
  x0 += k2; x1 += k0 + 5u;
#undef TFR
  return x0 ^ x1;
}

__device__ __forceinline__ uint32_t pkbf(float a, float b) {
  uint32_t ua = __float_as_uint(a), ub = __float_as_uint(b);
  ua = (ua + 0x7FFFu + ((ua >> 16) & 1u)) >> 16;
  ub = (ub + 0x7FFFu + ((ub >> 16) & 1u)) >> 16;
  return ua | (ub << 16);
}

// ---------------- K1: z = (log(10*clip(softmax64(u@tinyW))) + gumbel)/new_temp
__global__ __launch_bounds__(256) void k_z(
    const float* __restrict__ uu, const float* __restrict__ tw,
    const float* __restrict__ temp, float* __restrict__ Z) {
  __shared__ float tile[NK][65];
  const int tid = threadIdx.x;
  const int lane = tid & 63;      // = k
  const int wv = tid >> 6;
  const int d0 = blockIdx.x * 64;
  const float nt = fmaxf(0.1f, temp[0] * 0.99999f);
  float w[10];
#pragma unroll
  for (int i = 0; i < 10; ++i) w[i] = tw[i * NK + lane];
  for (int it = 0; it < 16; ++it) {
    const int dl = wv * 16 + it;
    const int d = d0 + dl;
    if (d < DD) {
      float m = 0.f;
#pragma unroll
      for (int i = 0; i < 10; ++i) m = fmaf(uu[d * 10 + i], w[i], m);
      float mx = m;
#pragma unroll
      for (int off = 32; off; off >>= 1) mx = fmaxf(mx, __shfl_xor(mx, off, 64));
      double e = exp((double)(m - mx));
      double ssum = e;
#pragma unroll
      for (int off = 32; off; off >>= 1) ssum += __shfl_xor(ssum, off, 64);
      float al = (float)(e / ssum);
      float c = fminf(fmaxf(al, 1e-7f), 0.9999999f);
      float lg = (float)log((double)(10.0f * c));
      const uint32_t bits = tf_bits((uint32_t)(lane * DD + d));
      float uf = __uint_as_float((bits >> 9) | 0x3f800000u) - 1.0f;
      float uv = fmaxf(1e-7f, uf * (1.0f - 1e-7f) + 1e-7f);
      float g = (float)(-log(-log((double)uv)));
      tile[lane][dl] = (lg + g) / nt;
    }
  }
  __syncthreads();
  for (int r0 = 0; r0 < NK; r0 += 4) {
    const int r = r0 + wv;
    const int d = d0 + lane;
    if (d < DD) Z[r * DD + d] = tile[r][lane];
  }
}

// ---------------- K2: per-row softmax + bf16 samples + exact top-64 ---------
__global__ __launch_bounds__(256) void k_rows(
    const float* __restrict__ Z, ushort* __restrict__ SBm,
    float* __restrict__ disc, float* __restrict__ cv, int* __restrict__ cc) {
  const int k = blockIdx.x;
  const int tid = threadIdx.x;
  __shared__ float redf[256];
  __shared__ double redd[256];
  __shared__ ull keys[2048];
  __shared__ ull wbest[4];
  const float* zr = Z + (size_t)k * DD;
  ushort* sbr = SBm + (size_t)k * DD;
  float* dr = disc + (size_t)k * DD;
  float mx = -1e30f;
  for (int d = tid; d < DD; d += 256) mx = fmaxf(mx, zr[d]);
  redf[tid] = mx;
  __syncthreads();
  for (int s = 128; s; s >>= 1) {
    if (tid < s) redf[tid] = fmaxf(redf[tid], redf[tid + s]);
    __syncthreads();
  }
  mx = redf[0];
  double psum = 0.0;
  for (int d = tid; d < DD; d += 256) psum += exp((double)(zr[d] - mx));
  redd[tid] = psum;
  __syncthreads();
  for (int s = 128; s; s >>= 1) {
    if (tid < s) redd[tid] += redd[tid + s];
    __syncthreads();
  }
  const double sumall = redd[0];
  float tv[8]; int tc[8];
#pragma unroll
  for (int s = 0; s < 8; ++s) { tv[s] = -1.f; tc[s] = 0; }
  for (int d = tid; d < DD; d += 256) {
    double e = exp((double)(zr[d] - mx));
    float svv = (float)(e / sumall);
    uint32_t ub = __float_as_uint(svv);
    sbr[d] = (ushort)((ub + 0x7FFFu + ((ub >> 16) & 1u)) >> 16);
    dr[d] = 0.f;
    if (svv > tv[7]) {
      float cvr = svv; int ccr = d;
#pragma unroll
      for (int s = 0; s < 8; ++s) {
        bool sw = cvr > tv[s];
        float nv = sw ? cvr : tv[s]; int nc = sw ? ccr : tc[s];
        cvr = sw ? tv[s] : cvr; ccr = sw ? tc[s] : ccr;
        tv[s] = nv; tc[s] = nc;
      }
    }
  }
#pragma unroll
  for (int s = 0; s < 8; ++s)
    keys[(tid << 3) + s] = (((ull)__float_as_uint(tv[s])) << 32)
                         | ((ull)(uint32_t)(32767 - tc[s]) << 11)
                         | ((ull)tid << 3) | (ull)s;
  __syncthreads();
  for (int t = 0; t < NK; ++t) {
    ull best = 0;
#pragma unroll
    for (int s = 0; s < 8; ++s) { ull kk = keys[(tid << 3) + s]; if (kk > best) best = kk; }
#pragma unroll
    for (int off = 32; off; off >>= 1) { ull o = __shfl_xor(best, off, 64); if (o > best) best = o; }
    if ((tid & 63) == 0) wbest[tid >> 6] = best;
    __syncthreads();
    ull win = wbest[0];
#pragma unroll
    for (int wI = 1; wI < 4; ++wI) if (wbest[wI] > win) win = wbest[wI];
    const uint32_t lo = (uint32_t)win;
    const int slot = lo & 7;
    const int owner = (lo >> 3) & 255;
    const int col = 32767 - (int)(lo >> 11);
    if (tid == 0) {
      cv[(k << 6) + t] = __uint_as_float((uint32_t)(win >> 32));
      cc[(k << 6) + t] = col;
    }
    if (tid == owner) keys[(owner << 3) + slot] = 0;
    __syncthreads();
  }
}

// ---------------- K3: greedy bipartite argmax-and-mask (1 wave) -------------
__global__ __launch_bounds__(64) void k_greedy(
    const float* __restrict__ cv, const int* __restrict__ cc,
    const float* __restrict__ temp, float* __restrict__ out) {
  __shared__ float v[NK][NK];
  __shared__ int c[NK][NK];
  __shared__ unsigned char used[DD];
  const int lane = threadIdx.x;
  for (int i = lane; i < DD; i += 64) used[i] = 0;
  for (int i = 0; i < NK; ++i) { v[i][lane] = cv[(i << 6) + lane]; c[i][lane] = cc[(i << 6) + lane]; }
  __syncthreads();
  int ptr = 0;
  bool done = false;
  for (int t = 0; t < NK; ++t) {
    ull key = 0;
    if (!done) {
      while (ptr < NK && used[c[lane][ptr]]) ++ptr;
      if (ptr < NK) {
        key = (((ull)__float_as_uint(v[lane][ptr])) << 21)
            | ((ull)(uint32_t)(63 - lane) << 15)
            | (ull)(uint32_t)(32767 - c[lane][ptr]);
      }
    }
#pragma unroll
    for (int off = 32; off; off >>= 1) { ull o = __shfl_xor(key, off, 64); if (o > key) key = o; }
    const int col = 32767 - (int)(key & 0x7FFF);
    const int row = 63 - (int)((key >> 15) & 63);
    if (lane == row) done = true;
    if (lane == 0) { used[col] = 1; out[YN + (size_t)row * DD + col] = 1.0f; }
    __syncthreads();
  }
  if (lane == 0) out[TOTN - 1] = fmaxf(0.1f, temp[0] * 0.99999f);
}

// ---------------- K4: zero Y (atomic accumulation target) -------------------
__global__ __launch_bounds__(256) void k_zeroY(float* __restrict__ out) {
  const int i = blockIdx.x * 256 + threadIdx.x;  // grid sized to YN/4 exactly
  ((float4*)out)[i] = make_float4(0.f, 0.f, 0.f, 0.f);
}

// ---------------- K5: Y = X @ samples^T — bf16 MFMA, register-direct --------
// Wave owns a 16-row m-strip x all 64 n. A: two float4/lane from X, cvt bf16.
// B: one uint4/lane per n-tile from bf16 samples (k-major, L2-resident).
// No LDS, no barriers; split-K=KS round-robin over 625 ksteps; atomic epilogue.
__global__ __launch_bounds__(256) void k_gemm(
    const float* __restrict__ X, const ushort* __restrict__ SBm,
    float* __restrict__ Y) {
  const int tid = threadIdx.x;
  const int lane = tid & 63;
  const int wv = tid >> 6;
  const int ksp = blockIdx.x;       // 0..KS-1
  const int m16 = lane & 15;
  const int kq = lane >> 4;         // 0..3
  const int mRow = blockIdx.y * 64 + wv * 16 + m16;
  const float* xp = X + (size_t)mRow * DD;
  const ushort* bp = SBm + (size_t)m16 * DD;
  f32x4 acc[4] = {{0,0,0,0},{0,0,0,0},{0,0,0,0},{0,0,0,0}};
  for (int s = ksp; s < 625; s += KS) {
    const int k0 = s * 32 + kq * 8;
    const float4 xa = *(const float4*)(xp + k0);
    const float4 xb = *(const float4*)(xp + k0 + 4);
    union { uint32_t u[4]; short8 v; } A;
    A.u[0] = pkbf(xa.x, xa.y); A.u[1] = pkbf(xa.z, xa.w);
    A.u[2] = pkbf(xb.x, xb.y); A.u[3] = pkbf(xb.z, xb.w);
#pragma unroll
    for (int nt = 0; nt < 4; ++nt) {
      union { uint4 q; short8 v; } B;
      B.q = *(const uint4*)(bp + (size_t)nt * 16 * DD + k0);
      acc[nt] = __builtin_amdgcn_mfma_f32_16x16x32_bf16(A.v, B.v, acc[nt], 0, 0, 0);
    }
  }
  const int rBase = blockIdx.y * 64 + wv * 16 + kq * 4;
#pragma unroll
  for (int nt = 0; nt < 4; ++nt)
#pragma unroll
    for (int r = 0; r < 4; ++r)
      atomicAdd(&Y[(size_t)(rBase + r) * 64 + nt * 16 + m16], acc[nt][r]);
}

extern "C" void kernel_launch(void* const* d_in, const int* in_sizes, int n_in,
                              void* d_out, int out_size, void* d_ws, size_t ws_size,
                              hipStream_t stream) {
  (void)in_sizes; (void)n_in; (void)out_size; (void)ws_size;
  const float* X = (const float*)d_in[0];
  const float* uu = (const float*)d_in[1];
  const float* tw = (const float*)d_in[2];
  const float* temp = (const float*)d_in[3];
  float* out = (float*)d_out;
  float* W = (float*)d_ws;
  float* Z = W + Z_OFF;
  float* CV = W + CV_OFF;
  int* CC = (int*)(W + CC_OFF);
  ushort* SBm = (ushort*)(W + SB_OFF);

  hipLaunchKernelGGL(k_zeroY, dim3(YN / 1024), dim3(256), 0, stream, out);
  hipLaunchKernelGGL(k_z, dim3(313), dim3(256), 0, stream, uu, tw, temp, Z);
  hipLaunchKernelGGL(k_rows, dim3(64), dim3(256), 0, stream, Z, SBm, out + YN, CV, CC);
  hipLaunchKernelGGL(k_greedy, dim3(1), dim3(64), 0, stream, CV, CC, temp, out);
  hipLaunchKernelGGL(k_gemm, dim3(KS, 64), dim3(256), 0, stream, X, SBm, out);
}

// Round 3
// 650.775 us; speedup vs baseline: 1.8910x; 1.0148x over previous
//
#include <hip/hip_runtime.h>
#include <stdint.h>
#include <math.h>

typedef unsigned long long ull;
typedef __attribute__((ext_vector_type(8))) short short8;
typedef __attribute__((ext_vector_type(4))) float f32x4;

#define DD 20000
#define NK 64
#define NB 4096
#define YN (NB * NK)              // 262144
#define TOTN (YN + NK * DD + 1)   // 1542145
#define KS 32                     // split-K factor for the GEMM

// ws byte offsets (ws_size ~1.31 GB per observed poison fills; we use ~46.5 MB)
#define E_OFF   0u                 // f64 exp(z) [64][20000]  = 10,240,000 B
#define RSP_OFF 10240000u          // f64 row partial sums [313][64] = 160,256 B
#define CV_OFF  10400256u          // f32 top-64 vals [64][64]
#define CC_OFF  10416640u          // i32 top-64 cols [64][64]
#define SB_OFF  10433024u          // bf16 samples [64][20000]
#define P_OFF   12993024u          // f32 GEMM partials [KS][4096][64] = 33,554,432 B

// ---------------- threefry2x32, JAX partitionable scheme ----------------
__device__ __forceinline__ uint32_t tf_bits(uint32_t j) {
  const uint32_t k0 = 0u, k1 = 42u;
  const uint32_t k2 = 0x1BD11BDAu ^ k0 ^ k1;
  uint32_t x0 = k0;
  uint32_t x1 = j + k1;
#define TFR(r) { x0 += x1; x1 = (x1 << r) | (x1 >> (32 - r)); x1 ^= x0; }
  TFR(13) TFR(15) TFR(26) TFR(6)
  x0 += k1; x1 += k2 + 1u;
  TFR(17) TFR(29) TFR(16) TFR(24)
  x0 += k2; x1 += k0 + 2u;
  TFR(13) TFR(15) TFR(26) TFR(6)
  x0 += k0; x1 += k1 + 3u;
  TFR(17) TFR(29) TFR(16) TFR(24)
  x0 += k1; x1 += k2 + 4u;
  TFR(13) TFR(15) TFR(26) TFR(6)
  x0 += k2; x1 += k0 + 5u;
#undef TFR
  return x0 ^ x1;
}

// ---------------- K1: e = exp((log(10*clip(sm64(u@W))) + gumbel)/nt), f64 ---
// Also emits per-block per-row partial sums RSP[block][k] (deterministic path).
__global__ __launch_bounds__(256) void k_z(
    const float* __restrict__ uu, const float* __restrict__ tw,
    const float* __restrict__ temp, double* __restrict__ E,
    double* __restrict__ RSP) {
  __shared__ double tile[NK][65];   // [k][dl], +1 pad
  __shared__ double psumw[4][NK];
  const int tid = threadIdx.x;
  const int lane = tid & 63;      // = k
  const int wv = tid >> 6;
  const int d0 = blockIdx.x * 64;
  const float nt = fmaxf(0.1f, temp[0] * 0.99999f);
  float w[10];
#pragma unroll
  for (int i = 0; i < 10; ++i) w[i] = tw[i * NK + lane];
  double psum = 0.0;
  for (int it = 0; it < 16; ++it) {
    const int dl = wv * 16 + it;
    const int d = d0 + dl;
    double e = 0.0;
    if (d < DD) {  // wave-uniform branch
      float m = 0.f;
#pragma unroll
      for (int i = 0; i < 10; ++i) m = fmaf(uu[d * 10 + i], w[i], m);
      float mx = m;
#pragma unroll
      for (int off = 32; off; off >>= 1) mx = fmaxf(mx, __shfl_xor(mx, off, 64));
      double ee = exp((double)(m - mx));
      double ssum = ee;
#pragma unroll
      for (int off = 32; off; off >>= 1) ssum += __shfl_xor(ssum, off, 64);
      float al = (float)(ee / ssum);
      float c = fminf(fmaxf(al, 1e-7f), 0.9999999f);
      float lg = (float)log((double)(10.0f * c));
      const uint32_t bits = tf_bits((uint32_t)(lane * DD + d));
      float uf = __uint_as_float((bits >> 9) | 0x3f800000u) - 1.0f;
      float uv = fmaxf(1e-7f, uf * (1.0f - 1e-7f) + 1e-7f);
      float g = (float)(-log(-log((double)uv)));
      float z = (lg + g) / nt;     // z in [-1.7, 1.9] -> no max-sub needed
      e = exp((double)z);
    }
    tile[lane][dl] = e;
    psum += e;
  }
  psumw[wv][lane] = psum;
  __syncthreads();
  for (int r0 = 0; r0 < NK; r0 += 4) {
    const int r = r0 + wv;
    const int d = d0 + lane;
    if (d < DD) E[(size_t)r * DD + d] = tile[r][lane];
  }
  if (wv == 0) {
    double s = psumw[0][lane] + psumw[1][lane] + psumw[2][lane] + psumw[3][lane];
    RSP[(size_t)blockIdx.x * NK + lane] = s;
  }
}

// ---------------- K2: samples (bf16) + zero discrete + exact top-64 ---------
__global__ __launch_bounds__(256) void k_rows(
    const double* __restrict__ E, const double* __restrict__ RSP,
    ushort* __restrict__ SBm, float* __restrict__ disc,
    float* __restrict__ cv, int* __restrict__ cc) {
  const int k = blockIdx.x;
  const int tid = threadIdx.x;
  __shared__ double redd[256];
  __shared__ ull keys[2048];
  __shared__ ull wbest[4];
  const double* er = E + (size_t)k * DD;
  ushort* sbr = SBm + (size_t)k * DD;
  float* dr = disc + (size_t)k * DD;
  // row sum from per-block partials (fixed order: deterministic)
  double psum = 0.0;
  for (int b = tid; b < 313; b += 256) psum += RSP[(size_t)b * NK + k];
  redd[tid] = psum;
  __syncthreads();
  for (int s = 128; s; s >>= 1) {
    if (tid < s) redd[tid] += redd[tid + s];
    __syncthreads();
  }
  const double sumall = redd[0];
  float tv[8]; int tc[8];
#pragma unroll
  for (int s = 0; s < 8; ++s) { tv[s] = -1.f; tc[s] = 0; }
  for (int d = tid; d < DD; d += 256) {
    float svv = (float)(er[d] / sumall);
    uint32_t ub = __float_as_uint(svv);
    sbr[d] = (ushort)((ub + 0x7FFFu + ((ub >> 16) & 1u)) >> 16);
    dr[d] = 0.f;
    if (svv > tv[7]) {
      float cvr = svv; int ccr = d;
#pragma unroll
      for (int s = 0; s < 8; ++s) {
        bool sw = cvr > tv[s];
        float nv = sw ? cvr : tv[s]; int nc = sw ? ccr : tc[s];
        cvr = sw ? tv[s] : cvr; ccr = sw ? tc[s] : ccr;
        tv[s] = nv; tc[s] = nc;
      }
    }
  }
#pragma unroll
  for (int s = 0; s < 8; ++s)
    keys[(tid << 3) + s] = (((ull)__float_as_uint(tv[s])) << 32)
                         | ((ull)(uint32_t)(32767 - tc[s]) << 11)
                         | ((ull)tid << 3) | (ull)s;
  __syncthreads();
  for (int t = 0; t < NK; ++t) {
    ull best = 0;
#pragma unroll
    for (int s = 0; s < 8; ++s) { ull kk = keys[(tid << 3) + s]; if (kk > best) best = kk; }
#pragma unroll
    for (int off = 32; off; off >>= 1) { ull o = __shfl_xor(best, off, 64); if (o > best) best = o; }
    if ((tid & 63) == 0) wbest[tid >> 6] = best;
    __syncthreads();
    ull win = wbest[0];
#pragma unroll
    for (int wI = 1; wI < 4; ++wI) if (wbest[wI] > win) win = wbest[wI];
    const uint32_t lo = (uint32_t)win;
    const int slot = lo & 7;
    const int owner = (lo >> 3) & 255;
    const int col = 32767 - (int)(lo >> 11);
    if (tid == 0) {
      cv[(k << 6) + t] = __uint_as_float((uint32_t)(win >> 32));
      cc[(k << 6) + t] = col;
    }
    if (tid == owner) keys[(owner << 3) + slot] = 0;
    __syncthreads();
  }
}

// ---------------- K3: greedy bipartite argmax-and-mask (1 wave) -------------
__global__ __launch_bounds__(64) void k_greedy(
    const float* __restrict__ cv, const int* __restrict__ cc,
    const float* __restrict__ temp, float* __restrict__ out) {
  __shared__ float v[NK][NK];
  __shared__ int c[NK][NK];
  __shared__ unsigned char used[DD];
  const int lane = threadIdx.x;
  for (int i = lane; i < DD; i += 64) used[i] = 0;
  for (int i = 0; i < NK; ++i) { v[i][lane] = cv[(i << 6) + lane]; c[i][lane] = cc[(i << 6) + lane]; }
  __syncthreads();
  int ptr = 0;
  bool done = false;
  for (int t = 0; t < NK; ++t) {
    ull key = 0;
    if (!done) {
      while (ptr < NK && used[c[lane][ptr]]) ++ptr;
      if (ptr < NK) {
        key = (((ull)__float_as_uint(v[lane][ptr])) << 21)
            | ((ull)(uint32_t)(63 - lane) << 15)
            | (ull)(uint32_t)(32767 - c[lane][ptr]);
      }
    }
#pragma unroll
    for (int off = 32; off; off >>= 1) { ull o = __shfl_xor(key, off, 64); if (o > key) key = o; }
    const int col = 32767 - (int)(key & 0x7FFF);
    const int row = 63 - (int)((key >> 15) & 63);
    if (lane == row) done = true;
    if (lane == 0) { used[col] = 1; out[YN + (size_t)row * DD + col] = 1.0f; }
    __syncthreads();
  }
  if (lane == 0) out[TOTN - 1] = fmaxf(0.1f, temp[0] * 0.99999f);
}

// ---------------- K4: Y-partials = X @ samples^T — bf16 MFMA, no atomics ----
__global__ __launch_bounds__(256) void k_gemm(
    const float* __restrict__ X, const ushort* __restrict__ SBm,
    float* __restrict__ P) {
  const int tid = threadIdx.x;
  const int lane = tid & 63;
  const int wv = tid >> 6;
  const int ksp = blockIdx.x;       // 0..KS-1
  const int m16 = lane & 15;
  const int kq = lane >> 4;         // 0..3
  const int mRow = blockIdx.y * 64 + wv * 16 + m16;
  const float* xp = X + (size_t)mRow * DD;
  const ushort* bp = SBm + (size_t)m16 * DD;
  f32x4 acc[4] = {{0,0,0,0},{0,0,0,0},{0,0,0,0},{0,0,0,0}};
#pragma unroll 2
  for (int s = ksp; s < 625; s += KS) {
    const int k0 = s * 32 + kq * 8;
    const float4 xa = *(const float4*)(xp + k0);
    const float4 xb = *(const float4*)(xp + k0 + 4);
    union { uint32_t u[4]; short8 v; } A;
    uint32_t ua0 = __float_as_uint(xa.x), ua1 = __float_as_uint(xa.y);
    uint32_t ua2 = __float_as_uint(xa.z), ua3 = __float_as_uint(xa.w);
    uint32_t ub0 = __float_as_uint(xb.x), ub1 = __float_as_uint(xb.y);
    uint32_t ub2 = __float_as_uint(xb.z), ub3 = __float_as_uint(xb.w);
    ua0 = (ua0 + 0x7FFFu + ((ua0 >> 16) & 1u)) >> 16;
    ua1 = (ua1 + 0x7FFFu + ((ua1 >> 16) & 1u)) >> 16;
    ua2 = (ua2 + 0x7FFFu + ((ua2 >> 16) & 1u)) >> 16;
    ua3 = (ua3 + 0x7FFFu + ((ua3 >> 16) & 1u)) >> 16;
    ub0 = (ub0 + 0x7FFFu + ((ub0 >> 16) & 1u)) >> 16;
    ub1 = (ub1 + 0x7FFFu + ((ub1 >> 16) & 1u)) >> 16;
    ub2 = (ub2 + 0x7FFFu + ((ub2 >> 16) & 1u)) >> 16;
    ub3 = (ub3 + 0x7FFFu + ((ub3 >> 16) & 1u)) >> 16;
    A.u[0] = ua0 | (ua1 << 16); A.u[1] = ua2 | (ua3 << 16);
    A.u[2] = ub0 | (ub1 << 16); A.u[3] = ub2 | (ub3 << 16);
#pragma unroll
    for (int nt = 0; nt < 4; ++nt) {
      union { uint4 q; short8 v; } B;
      B.q = *(const uint4*)(bp + (size_t)nt * 16 * DD + k0);
      acc[nt] = __builtin_amdgcn_mfma_f32_16x16x32_bf16(A.v, B.v, acc[nt], 0, 0, 0);
    }
  }
  float* pp = P + (size_t)ksp * YN;
  const int rBase = blockIdx.y * 64 + wv * 16 + kq * 4;
#pragma unroll
  for (int nt = 0; nt < 4; ++nt)
#pragma unroll
    for (int r = 0; r < 4; ++r)
      pp[(size_t)(rBase + r) * 64 + nt * 16 + m16] = acc[nt][r];
}

// ---------------- K5: reduce KS partials -> Y ------------------------------
__global__ __launch_bounds__(256) void k_gred(const float* __restrict__ P,
                                              float* __restrict__ Y) {
  const int i = blockIdx.x * 256 + threadIdx.x;   // grid = YN/4/256 = 256
  float4 a = ((const float4*)P)[i];
#pragma unroll
  for (int j = 1; j < KS; ++j) {
    const float4 b = ((const float4*)(P + (size_t)j * YN))[i];
    a.x += b.x; a.y += b.y; a.z += b.z; a.w += b.w;
  }
  ((float4*)Y)[i] = a;
}

extern "C" void kernel_launch(void* const* d_in, const int* in_sizes, int n_in,
                              void* d_out, int out_size, void* d_ws, size_t ws_size,
                              hipStream_t stream) {
  (void)in_sizes; (void)n_in; (void)out_size; (void)ws_size;
  const float* X = (const float*)d_in[0];
  const float* uu = (const float*)d_in[1];
  const float* tw = (const float*)d_in[2];
  const float* temp = (const float*)d_in[3];
  float* out = (float*)d_out;
  char* W = (char*)d_ws;
  double* E   = (double*)(W + E_OFF);
  double* RSP = (double*)(W + RSP_OFF);
  float*  CV  = (float*)(W + CV_OFF);
  int*    CC  = (int*)(W + CC_OFF);
  ushort* SBm = (ushort*)(W + SB_OFF);
  float*  P   = (float*)(W + P_OFF);

  hipLaunchKernelGGL(k_z, dim3(313), dim3(256), 0, stream, uu, tw, temp, E, RSP);
  hipLaunchKernelGGL(k_rows, dim3(64), dim3(256), 0, stream, E, RSP, SBm, out + YN, CV, CC);
  hipLaunchKernelGGL(k_greedy, dim3(1), dim3(64), 0, stream, CV, CC, temp, out);
  hipLaunchKernelGGL(k_gemm, dim3(KS, 64), dim3(256), 0, stream, X, SBm, P);
  hipLaunchKernelGGL(k_gred, dim3(256), dim3(256), 0, stream, P, out);
}

// Round 4
// 649.164 us; speedup vs baseline: 1.8957x; 1.0025x over previous
//
#include <hip/hip_runtime.h>
#include <stdint.h>
#include <math.h>

typedef unsigned long long ull;
typedef __attribute__((ext_vector_type(8))) short short8;
typedef __attribute__((ext_vector_type(4))) float f32x4;

#define DD 20000
#define NK 64
#define NB 4096
#define YN (NB * NK)              // 262144
#define TOTN (YN + NK * DD + 1)   // 1542145
#define KS 16                     // split-K factor for the GEMM

// ws byte offsets (~29.8 MB used)
#define E_OFF   0u                 // f64 e = exp(z) [64][20000]
#define RSP_OFF 10240000u          // f64 row partial sums [313][64]
#define CV_OFF  10400256u          // f32 top-64 vals [64][64]
#define CC_OFF  10416640u          // i32 top-64 cols [64][64]
#define EB_OFF  10433024u          // bf16 e [64][20000] (ushort)
#define IRS_OFF 12993024u          // f32 1/rowsum [64]
#define P_OFF   12993280u          // f32 GEMM partials [KS][4096][64]

// ---------------- threefry2x32, JAX partitionable scheme ----------------
__device__ __forceinline__ uint32_t tf_bits(uint32_t j) {
  const uint32_t k0 = 0u, k1 = 42u;
  const uint32_t k2 = 0x1BD11BDAu ^ k0 ^ k1;
  uint32_t x0 = k0;
  uint32_t x1 = j + k1;
#define TFR(r) { x0 += x1; x1 = (x1 << r) | (x1 >> (32 - r)); x1 ^= x0; }
  TFR(13) TFR(15) TFR(26) TFR(6)
  x0 += k1; x1 += k2 + 1u;
  TFR(17) TFR(29) TFR(16) TFR(24)
  x0 += k2; x1 += k0 + 2u;
  TFR(13) TFR(15) TFR(26) TFR(6)
  x0 += k0; x1 += k1 + 3u;
  TFR(17) TFR(29) TFR(16) TFR(24)
  x0 += k1; x1 += k2 + 4u;
  TFR(13) TFR(15) TFR(26) TFR(6)
  x0 += k2; x1 += k0 + 5u;
#undef TFR
  return x0 ^ x1;
}

// ---------------- K1: e = exp((log(10*clip(sm64(u@W))) + gumbel)/nt) --------
// Emits: E (f64), EB (bf16), RSP row partial sums, and zeroes the discrete
// output slice for this block's 64 columns (coalesced float4).
__global__ __launch_bounds__(256) void k_z(
    const float* __restrict__ uu, const float* __restrict__ tw,
    const float* __restrict__ temp, double* __restrict__ E,
    ushort* __restrict__ EB, double* __restrict__ RSP,
    float* __restrict__ disc) {
  __shared__ double tile[NK][65];   // [k][dl], +1 pad
  __shared__ double psumw[4][NK];
  const int tid = threadIdx.x;
  const int lane = tid & 63;      // = k
  const int wv = tid >> 6;
  const int d0 = blockIdx.x * 64;
  const float nt = fmaxf(0.1f, temp[0] * 0.99999f);
  float w[10];
#pragma unroll
  for (int i = 0; i < 10; ++i) w[i] = tw[i * NK + lane];
  double psum = 0.0;
  for (int it = 0; it < 16; ++it) {
    const int dl = wv * 16 + it;
    const int d = d0 + dl;
    double e = 0.0;
    if (d < DD) {  // wave-uniform branch
      float m = 0.f;
#pragma unroll
      for (int i = 0; i < 10; ++i) m = fmaf(uu[d * 10 + i], w[i], m);
      float mx = m;
#pragma unroll
      for (int off = 32; off; off >>= 1) mx = fmaxf(mx, __shfl_xor(mx, off, 64));
      double ee = exp((double)(m - mx));
      double ssum = ee;
#pragma unroll
      for (int off = 32; off; off >>= 1) ssum += __shfl_xor(ssum, off, 64);
      float al = (float)(ee / ssum);
      float c = fminf(fmaxf(al, 1e-7f), 0.9999999f);
      float lg = (float)log((double)(10.0f * c));
      const uint32_t bits = tf_bits((uint32_t)(lane * DD + d));
      float uf = __uint_as_float((bits >> 9) | 0x3f800000u) - 1.0f;
      float uv = fmaxf(1e-7f, uf * (1.0f - 1e-7f) + 1e-7f);
      float g = (float)(-log(-log((double)uv)));
      float z = (lg + g) / nt;     // z in [-1.7, 1.9] -> no max-sub needed
      e = exp((double)z);
    }
    tile[lane][dl] = e;
    psum += e;
  }
  psumw[wv][lane] = psum;
  __syncthreads();
  for (int r0 = 0; r0 < NK; r0 += 4) {
    const int r = r0 + wv;
    const int d = d0 + lane;
    if (d < DD) {
      const double ev = tile[r][lane];
      E[(size_t)r * DD + d] = ev;
      const float ef = (float)ev;
      uint32_t ub = __float_as_uint(ef);
      EB[(size_t)r * DD + d] = (ushort)((ub + 0x7FFFu + ((ub >> 16) & 1u)) >> 16);
    }
  }
  if (wv == 0) {
    double s = psumw[0][lane] + psumw[1][lane] + psumw[2][lane] + psumw[3][lane];
    RSP[(size_t)blockIdx.x * NK + lane] = s;
  }
  // zero the discrete slice: cols [d0, d0+64) x 64 rows, float4 stores
  const int cg = tid & 15;         // col group (4 cols)
  const int r0 = tid >> 4;         // 0..15
  if (d0 + cg * 4 < DD) {
    for (int r = r0; r < NK; r += 16)
      *(float4*)(disc + (size_t)r * DD + d0 + cg * 4) = make_float4(0.f, 0.f, 0.f, 0.f);
  }
}

// ---------------- K2: row sums + exact top-64 (raw e order == samples order)
__global__ __launch_bounds__(256) void k_rows(
    const double* __restrict__ E, const double* __restrict__ RSP,
    float* __restrict__ cv, int* __restrict__ cc, float* __restrict__ invRS) {
  const int k = blockIdx.x;
  const int tid = threadIdx.x;
  __shared__ double redd[256];
  __shared__ ull keys[2048];
  __shared__ ull wbest[4];
  const double* er = E + (size_t)k * DD;
  double psum = 0.0;
  for (int b = tid; b < 313; b += 256) psum += RSP[(size_t)b * NK + k];
  redd[tid] = psum;
  __syncthreads();
  for (int s = 128; s; s >>= 1) {
    if (tid < s) redd[tid] += redd[tid + s];
    __syncthreads();
  }
  const double sumall = redd[0];
  if (tid == 0) invRS[k] = (float)(1.0 / sumall);
  float tv[8]; int tc[8];
#pragma unroll
  for (int s = 0; s < 8; ++s) { tv[s] = -1.f; tc[s] = 0; }
  for (int d = tid; d < DD; d += 256) {
    float svv = (float)(er[d] / sumall);   // same bits as samples (f32)
    if (svv > tv[7]) {
      float cvr = svv; int ccr = d;
#pragma unroll
      for (int s = 0; s < 8; ++s) {
        bool sw = cvr > tv[s];
        float nv = sw ? cvr : tv[s]; int nc = sw ? ccr : tc[s];
        cvr = sw ? tv[s] : cvr; ccr = sw ? tc[s] : ccr;
        tv[s] = nv; tc[s] = nc;
      }
    }
  }
#pragma unroll
  for (int s = 0; s < 8; ++s)
    keys[(tid << 3) + s] = (((ull)__float_as_uint(tv[s])) << 32)
                         | ((ull)(uint32_t)(32767 - tc[s]) << 11)
                         | ((ull)tid << 3) | (ull)s;
  __syncthreads();
  for (int t = 0; t < NK; ++t) {
    ull best = 0;
#pragma unroll
    for (int s = 0; s < 8; ++s) { ull kk = keys[(tid << 3) + s]; if (kk > best) best = kk; }
#pragma unroll
    for (int off = 32; off; off >>= 1) { ull o = __shfl_xor(best, off, 64); if (o > best) best = o; }
    if ((tid & 63) == 0) wbest[tid >> 6] = best;
    __syncthreads();
    ull win = wbest[0];
#pragma unroll
    for (int wI = 1; wI < 4; ++wI) if (wbest[wI] > win) win = wbest[wI];
    const uint32_t lo = (uint32_t)win;
    const int slot = lo & 7;
    const int owner = (lo >> 3) & 255;
    const int col = 32767 - (int)(lo >> 11);
    if (tid == 0) {
      cv[(k << 6) + t] = __uint_as_float((uint32_t)(win >> 32));
      cc[(k << 6) + t] = col;
    }
    if (tid == owner) keys[(owner << 3) + slot] = 0;
    __syncthreads();
  }
}

// ---------------- K3: greedy bipartite argmax-and-mask (1 wave) -------------
__global__ __launch_bounds__(64) void k_greedy(
    const float* __restrict__ cv, const int* __restrict__ cc,
    const float* __restrict__ temp, float* __restrict__ out) {
  __shared__ float vf[NK * NK];
  __shared__ int cf[NK * NK];
  __shared__ unsigned char used[DD];
  const int lane = threadIdx.x;
  for (int i = lane; i < DD; i += 64) used[i] = 0;
  for (int i = lane; i < 1024; i += 64) {
    ((float4*)vf)[i] = ((const float4*)cv)[i];
    ((int4*)cf)[i] = ((const int4*)cc)[i];
  }
  __syncthreads();
  int ptr = 0;
  bool done = false;
  for (int t = 0; t < NK; ++t) {
    ull key = 0;
    if (!done) {
      while (ptr < NK && used[cf[(lane << 6) + ptr]]) ++ptr;
      if (ptr < NK) {
        key = (((ull)__float_as_uint(vf[(lane << 6) + ptr])) << 21)
            | ((ull)(uint32_t)(63 - lane) << 15)
            | (ull)(uint32_t)(32767 - cf[(lane << 6) + ptr]);
      }
    }
#pragma unroll
    for (int off = 32; off; off >>= 1) { ull o = __shfl_xor(key, off, 64); if (o > key) key = o; }
    const int col = 32767 - (int)(key & 0x7FFF);
    const int row = 63 - (int)((key >> 15) & 63);
    if (lane == row) done = true;
    if (lane == 0) { used[col] = 1; out[YN + (size_t)row * DD + col] = 1.0f; }
    __syncthreads();
  }
  if (lane == 0) out[TOTN - 1] = fmaxf(0.1f, temp[0] * 0.99999f);
}

// ---------------- K4: P[ksp] = X @ bf16(e)^T — bf16 MFMA, register-direct ---
__global__ __launch_bounds__(256) void k_gemm(
    const float* __restrict__ X, const ushort* __restrict__ EB,
    float* __restrict__ P) {
  const int tid = threadIdx.x;
  const int lane = tid & 63;
  const int wv = tid >> 6;
  const int ksp = blockIdx.x;       // 0..KS-1
  const int m16 = lane & 15;
  const int kq = lane >> 4;         // 0..3
  const int mRow = blockIdx.y * 64 + wv * 16 + m16;
  const float* xp = X + (size_t)mRow * DD;
  const ushort* bp = EB + (size_t)m16 * DD;
  f32x4 acc[4] = {{0,0,0,0},{0,0,0,0},{0,0,0,0},{0,0,0,0}};
#pragma unroll 2
  for (int s = ksp; s < 625; s += KS) {
    const int k0 = s * 32 + kq * 8;
    const float4 xa = *(const float4*)(xp + k0);
    const float4 xb = *(const float4*)(xp + k0 + 4);
    union { uint4 q[4]; short8 v[4]; } B;
#pragma unroll
    for (int nt = 0; nt < 4; ++nt)
      B.q[nt] = *(const uint4*)(bp + (size_t)nt * 16 * DD + k0);
    union { uint32_t u[4]; short8 v; } A;
    uint32_t ua0 = __float_as_uint(xa.x), ua1 = __float_as_uint(xa.y);
    uint32_t ua2 = __float_as_uint(xa.z), ua3 = __float_as_uint(xa.w);
    uint32_t ub0 = __float_as_uint(xb.x), ub1 = __float_as_uint(xb.y);
    uint32_t ub2 = __float_as_uint(xb.z), ub3 = __float_as_uint(xb.w);
    ua0 = (ua0 + 0x7FFFu + ((ua0 >> 16) & 1u)) >> 16;
    ua1 = (ua1 + 0x7FFFu + ((ua1 >> 16) & 1u)) >> 16;
    ua2 = (ua2 + 0x7FFFu + ((ua2 >> 16) & 1u)) >> 16;
    ua3 = (ua3 + 0x7FFFu + ((ua3 >> 16) & 1u)) >> 16;
    ub0 = (ub0 + 0x7FFFu + ((ub0 >> 16) & 1u)) >> 16;
    ub1 = (ub1 + 0x7FFFu + ((ub1 >> 16) & 1u)) >> 16;
    ub2 = (ub2 + 0x7FFFu + ((ub2 >> 16) & 1u)) >> 16;
    ub3 = (ub3 + 0x7FFFu + ((ub3 >> 16) & 1u)) >> 16;
    A.u[0] = ua0 | (ua1 << 16); A.u[1] = ua2 | (ua3 << 16);
    A.u[2] = ub0 | (ub1 << 16); A.u[3] = ub2 | (ub3 << 16);
#pragma unroll
    for (int nt = 0; nt < 4; ++nt)
      acc[nt] = __builtin_amdgcn_mfma_f32_16x16x32_bf16(A.v, B.v[nt], acc[nt], 0, 0, 0);
  }
  float* pp = P + (size_t)ksp * YN;
  const int rBase = blockIdx.y * 64 + wv * 16 + kq * 4;
#pragma unroll
  for (int nt = 0; nt < 4; ++nt)
#pragma unroll
    for (int r = 0; r < 4; ++r)
      pp[(size_t)(rBase + r) * 64 + nt * 16 + m16] = acc[nt][r];
}

// ---------------- K5: Y = (sum of KS partials) * invRS[col] -----------------
__global__ __launch_bounds__(256) void k_gred(const float* __restrict__ P,
                                              const float* __restrict__ invRS,
                                              float* __restrict__ Y) {
  const int i = blockIdx.x * 256 + threadIdx.x;   // grid = YN/4/256 = 256
  float4 a = ((const float4*)P)[i];
#pragma unroll
  for (int j = 1; j < KS; ++j) {
    const float4 b = ((const float4*)(P + (size_t)j * YN))[i];
    a.x += b.x; a.y += b.y; a.z += b.z; a.w += b.w;
  }
  const float4 irs = *(const float4*)(invRS + ((i * 4) & 63));
  a.x *= irs.x; a.y *= irs.y; a.z *= irs.z; a.w *= irs.w;
  ((float4*)Y)[i] = a;
}

extern "C" void kernel_launch(void* const* d_in, const int* in_sizes, int n_in,
                              void* d_out, int out_size, void* d_ws, size_t ws_size,
                              hipStream_t stream) {
  (void)in_sizes; (void)n_in; (void)out_size; (void)ws_size;
  const float* X = (const float*)d_in[0];
  const float* uu = (const float*)d_in[1];
  const float* tw = (const float*)d_in[2];
  const float* temp = (const float*)d_in[3];
  float* out = (float*)d_out;
  char* W = (char*)d_ws;
  double* E   = (double*)(W + E_OFF);
  double* RSP = (double*)(W + RSP_OFF);
  float*  CV  = (float*)(W + CV_OFF);
  int*    CC  = (int*)(W + CC_OFF);
  ushort* EB  = (ushort*)(W + EB_OFF);
  float*  IRS = (float*)(W + IRS_OFF);
  float*  P   = (float*)(W + P_OFF);

  hipLaunchKernelGGL(k_z, dim3(313), dim3(256), 0, stream, uu, tw, temp, E, EB, RSP, out + YN);
  hipLaunchKernelGGL(k_gemm, dim3(KS, 64), dim3(256), 0, stream, X, EB, P);
  hipLaunchKernelGGL(k_rows, dim3(64), dim3(256), 0, stream, E, RSP, CV, CC, IRS);
  hipLaunchKernelGGL(k_greedy, dim3(1), dim3(64), 0, stream, CV, CC, temp, out);
  hipLaunchKernelGGL(k_gred, dim3(256), dim3(256), 0, stream, P, IRS, out);
}